// Round 7
// baseline (33267.087 us; speedup 1.0000x reference)
//
#include <hip/hip_runtime.h>
#include <math.h>

// h_t = tanh(A h_{t-1} + B x_t + c), A = 0.9 I + 0.1 A_raw
// T=16384, X=512, H=1024, fp32. Output: all h_t, [T, H].
//
// Phase 1: Bx = x @ B^T + c written in-place into d_out.
// Phase 2: tagged-slot pipeline (validated: 64 blocks x 512 threads, 4-deep
//   global ring, sc0 sc1 transport). Round-7 changes the DETECTION path:
//
//   WHY: step = ~2980cy, ~2400 of it communication. The register-poll's
//   sampling period is RT-quantized (vmcnt(0) inside asm is mandatory for
//   register targets -- rounds 3-5 proved in-flight register loads across
//   compiler code are unsound). A poll that narrowly misses visibility
//   pays a full extra RT (~900-1200cy).
//
//   MECHANISM (register-hazard-free counted polling):
//   - Poll via global_load_lds (LLC -> LDS scratch DMA, aux=sc0|sc1=17).
//     In-flight DMAs write FIXED LDS addresses, not VGPRs -> no live-range
//     hazard -> counted s_waitcnt vmcnt(3) is sound. 4 slots per wave,
//     round-robin: sampling period ~max(RT/4, ds_read check ~130cy).
//   - Check = raw asm ds_read_b128 + lgkmcnt(0) (synchronous; hlds/pscr
//     are distinct LDS objects, so compiler LDS-DMA alias tracking should
//     not force drains around the exchange).
//   - Step-top s_waitcnt vmcnt(3): the 3 stragglers from the previous
//     step's poll are the 3 OLDEST vmem ops (queue: g,g,g,bxn,pkt,out) ->
//     vmcnt(3) retires exactly them before slot reuse (torn-write safety)
//     WITHOUT draining store-acks/prefetch.
//   - Raw barrier (lgkmcnt(0) + s_barrier, no vmcnt drain): required so
//     stragglers/prefetch/acks ride through and retire under compute.
//     LDS exchange correctness needs only lgkmcnt(0).
//   - Tags make every stale/straggler write self-identifying: leftover
//     scratch holds tag <= t, expected tag at step t+1 is t+1 -> no false
//     accept, ever. Misses only cost extra samples.
//   - ESCALATION: after 12 LDS-poll misses, vmcnt(0) drain + validated
//     register poll (always live). Bounds the cost if the LDS-DMA path
//     cannot see fresh LLC data.
//   Arithmetic is bit-identical to round 6 (absmax must be 0.00390625).

#define T_STEPS 16384
#define XD 512
#define HD 1024

typedef unsigned int uint32x4 __attribute__((ext_vector_type(4)));

#define DPP_ADD(v, ctrl, rm)                                          \
    v += __int_as_float(__builtin_amdgcn_update_dpp(                  \
        0, __float_as_int(v), ctrl, rm, 0xf, true))

__device__ __forceinline__ float fast_tanh(float x)
{
    const float e = __expf(2.0f * x);
    return 1.0f - 2.0f / (e + 1.0f);
}

// ---------------------------------------------------------------------------
// Phase 1: GEMM  out[t][i] = sum_k x[t][k] * B[i][k] + c[i]   (unchanged)
// ---------------------------------------------------------------------------
__global__ __launch_bounds__(256) void gemm_bx_kernel(
    const float* __restrict__ x, const float* __restrict__ B,
    const float* __restrict__ c, float* __restrict__ out)
{
    __shared__ __align__(16) float xs[32][68];  // [k][t]
    __shared__ __align__(16) float bs[32][68];  // [k][i]

    const int tid = threadIdx.x;
    const int t0 = blockIdx.x * 64;
    const int i0 = blockIdx.y * 64;
    const int tx = tid & 15;
    const int ty = tid >> 4;
    const int lr = tid >> 3;
    const int lc = (tid & 7) << 2;

    float acc[4][4] = {{0.f}};

    for (int k0 = 0; k0 < XD; k0 += 32) {
        const float4 xa = *(const float4*)&x[(size_t)(t0 + lr) * XD + k0 + lc];
        const float4 xb = *(const float4*)&x[(size_t)(t0 + lr + 32) * XD + k0 + lc];
        const float4 ba = *(const float4*)&B[(size_t)(i0 + lr) * XD + k0 + lc];
        const float4 bb = *(const float4*)&B[(size_t)(i0 + lr + 32) * XD + k0 + lc];
        __syncthreads();
        xs[lc + 0][lr] = xa.x; xs[lc + 1][lr] = xa.y; xs[lc + 2][lr] = xa.z; xs[lc + 3][lr] = xa.w;
        xs[lc + 0][lr + 32] = xb.x; xs[lc + 1][lr + 32] = xb.y; xs[lc + 2][lr + 32] = xb.z; xs[lc + 3][lr + 32] = xb.w;
        bs[lc + 0][lr] = ba.x; bs[lc + 1][lr] = ba.y; bs[lc + 2][lr] = ba.z; bs[lc + 3][lr] = ba.w;
        bs[lc + 0][lr + 32] = bb.x; bs[lc + 1][lr + 32] = bb.y; bs[lc + 2][lr + 32] = bb.z; bs[lc + 3][lr + 32] = bb.w;
        __syncthreads();
        #pragma unroll
        for (int k = 0; k < 32; ++k) {
            const float4 av = *(const float4*)&xs[k][ty << 2];
            const float4 bv = *(const float4*)&bs[k][tx << 2];
            const float am[4] = {av.x, av.y, av.z, av.w};
            const float bn[4] = {bv.x, bv.y, bv.z, bv.w};
            #pragma unroll
            for (int m = 0; m < 4; ++m)
                #pragma unroll
                for (int n = 0; n < 4; ++n)
                    acc[m][n] = fmaf(am[m], bn[n], acc[m][n]);
        }
    }

    #pragma unroll
    for (int m = 0; m < 4; ++m) {
        const int trow = t0 + (ty << 2) + m;
        #pragma unroll
        for (int n = 0; n < 4; ++n) {
            const int icol = i0 + (tx << 2) + n;
            out[(size_t)trow * HD + icol] = acc[m][n] + c[icol];
        }
    }
}

// ---------------------------------------------------------------------------
// Slot-ring init (d_ws is poisoned 0xAA before every launch).
// ---------------------------------------------------------------------------
__global__ void init_slots_kernel(unsigned long long* slots, const float* h0)
{
    const int i = threadIdx.x;  // 1024 threads
    union { float f; unsigned u; } v; v.f = h0[i];
    slots[3 * HD + i] = (unsigned long long)v.u;          // tag 0 | h0 bits
    slots[0 * HD + i] = 0xFFFFFFFF00000000ull;
    slots[1 * HD + i] = 0xFFFFFFFF00000000ull;
    slots[2 * HD + i] = 0xFFFFFFFF00000000ull;
}

// ---------------------------------------------------------------------------
// Phase 2: tagged-slot scan. 64 blocks x 512 threads; wave w owns rows
// 16*bid + 2w and 16*bid + 2w + 1.
// ---------------------------------------------------------------------------
__global__ __launch_bounds__(512) void rnn_scan_kernel(
    const float* __restrict__ A_raw, float* out,
    unsigned long long* slots)
{
    const int tid = threadIdx.x;       // 0..511
    const int bid = blockIdx.x;        // 0..63
    const int wave = tid >> 6;         // 0..7
    const int lane = tid & 63;
    const int r0 = (bid << 4) + (wave << 1);   // rows r0, r0+1

    __shared__ float hlds[2][HD];                         // 8 KiB exchange
    __shared__ __align__(16) unsigned pscr[8][4][256];    // 32 KiB poll scratch
    // pscr[wave][slot][lane*4 + w]: global_load_lds lands lane L's 16B
    // packet at base + 16*L (linear wave-uniform-base semantics).

    float aw0[16], aw1[16];
    #pragma unroll
    for (int j = 0; j < 16; ++j) {
        const int k = lane + (j << 6);
        float v0 = 0.1f * A_raw[(size_t)r0 * HD + k];
        float v1 = 0.1f * A_raw[(size_t)(r0 + 1) * HD + k];
        if (k == r0) v0 += 0.9f;
        if (k == r0 + 1) v1 += 0.9f;
        aw0[j] = v0; aw1[j] = v1;
    }

    // Scratch tag init: impossible tags so step-0 checks can't false-match.
    #pragma unroll
    for (int s = 0; s < 4; ++s) {
        pscr[wave][s][(lane << 2) + 1] = 0xFFFFFFFFu;
        pscr[wave][s][(lane << 2) + 3] = 0xFFFFFFFFu;
    }
    __syncthreads();

    // Prefetch Bx for t=0.
    float2 bxn = *(const float2*)&out[r0];

    for (int t = 0; t < T_STEPS; ++t) {
        const unsigned long long* sp =
            slots + ((size_t)((t + 3) & 3) << 10) + (tid << 1);

        // Step-top counted drain: retire the previous step's <=3 poll-DMA
        // stragglers (the 3 OLDEST vmem ops; bxn/pkt/out may stay).
        asm volatile("s_waitcnt vmcnt(3)" ::: "memory");
        __builtin_amdgcn_sched_barrier(0);

        // Issue 4 pipelined LLC->LDS pollers (aux=17: sc0|sc1).
        #pragma unroll
        for (int s2 = 0; s2 < 4; ++s2)
            __builtin_amdgcn_global_load_lds(sp, &pscr[wave][s2][0], 16, 0, 17);

        // Counted poll: wait oldest DMA (vmcnt(3)), ds_read-check, reissue.
        float2 hv;
        for (int i = 0; ; ++i) {
            const int slot = i & 3;
            asm volatile("s_waitcnt vmcnt(3)" ::: "memory");
            __builtin_amdgcn_sched_barrier(0);
            uint32x4 pk;
            const unsigned la =
                (unsigned)(size_t)&pscr[wave][slot][lane << 2];
            asm volatile("ds_read_b128 %0, %1\n\t"
                         "s_waitcnt lgkmcnt(0)"
                         : "=&v"(pk) : "v"(la));
            __builtin_amdgcn_sched_barrier(0);
            if (pk.y == (unsigned)t && pk.w == (unsigned)t) {
                hv = make_float2(__uint_as_float(pk.x), __uint_as_float(pk.z));
                break;   // exactly 3 stragglers in flight (LDS-only targets)
            }
            if (i == 12) {
                // Escalation: drain, then validated register poll.
                asm volatile("s_waitcnt vmcnt(0)" ::: "memory");
                uint32x4 s3;
                do {
                    asm volatile(
                        "global_load_dwordx4 %0, %1, off sc0 sc1\n\t"
                        "s_waitcnt vmcnt(0)"
                        : "=v"(s3) : "v"(sp));
                } while (s3.y != (unsigned)t || s3.w != (unsigned)t);
                hv = make_float2(__uint_as_float(s3.x), __uint_as_float(s3.z));
                break;   // 0 in flight on this path
            }
            __builtin_amdgcn_global_load_lds(sp, &pscr[wave][slot][0], 16, 0, 17);
        }

        // Capture this step's Bx BEFORE overwriting the prefetch register.
        const float2 bx = bxn;

        // Exchange via LDS (hlds and pscr are distinct LDS objects).
        *(float2*)&hlds[t & 1][tid << 1] = make_float2(hv.x, hv.y);

        // Prefetch next step's Bx; retires under compute / next step-top.
        const int tn = (t + 1 < T_STEPS) ? (t + 1) : t;
        bxn = *(const float2*)&out[(size_t)tn * HD + r0];

        // Raw barrier: LDS ordering only; in-flight vmem rides through.
        asm volatile("s_waitcnt lgkmcnt(0)\n\t"
                     "s_barrier" ::: "memory");

        // Both rows' dot products from ONE pass over h in LDS.
        const float* hl = hlds[t & 1];
        float p0 = 0.f, p1 = 0.f;
        #pragma unroll
        for (int j = 0; j < 16; ++j) {
            const float hvj = hl[lane + (j << 6)];
            p0 = fmaf(aw0[j], hvj, p0);
            p1 = fmaf(aw1[j], hvj, p1);
        }

        // Wave-wide sums via DPP (validated round 6); full sum in lane 63.
        DPP_ADD(p0, 0x111, 0xf); DPP_ADD(p1, 0x111, 0xf);  // row_shr:1
        DPP_ADD(p0, 0x112, 0xf); DPP_ADD(p1, 0x112, 0xf);  // row_shr:2
        DPP_ADD(p0, 0x114, 0xf); DPP_ADD(p1, 0x114, 0xf);  // row_shr:4
        DPP_ADD(p0, 0x118, 0xf); DPP_ADD(p1, 0x118, 0xf);  // row_shr:8
        DPP_ADD(p0, 0x142, 0xa); DPP_ADD(p1, 0x142, 0xa);  // row_bcast:15
        DPP_ADD(p0, 0x143, 0xc); DPP_ADD(p1, 0x143, 0xc);  // row_bcast:31

        if (lane == 63) {
            const float h0n = fast_tanh(p0 + bx.x);
            const float h1n = fast_tanh(p1 + bx.y);
            union { float f; unsigned u; } u0, u1; u0.f = h0n; u1.f = h1n;
            uint32x4 pkt;
            pkt.x = u0.u; pkt.y = (unsigned)(t + 1);
            pkt.z = u1.u; pkt.w = (unsigned)(t + 1);
            unsigned long long* dp = slots + ((size_t)(t & 3) << 10) + r0;
            asm volatile(
                "global_store_dwordx4 %0, %1, off sc0 sc1"
                :: "v"(dp), "v"(pkt) : "memory");
            *(float2*)&out[(size_t)t * HD + r0] = make_float2(h0n, h1n);
        }
        // No grid barrier: tags + 4-deep ring + dataflow (skew <= 1).
    }

    // Retire any still-pending poll DMAs before the wave ends.
    asm volatile("s_waitcnt vmcnt(0)" ::: "memory");
}

// ---------------------------------------------------------------------------
extern "C" void kernel_launch(void* const* d_in, const int* in_sizes, int n_in,
                              void* d_out, int out_size, void* d_ws, size_t ws_size,
                              hipStream_t stream)
{
    const float* x     = (const float*)d_in[0];  // [16384, 512]
    const float* h0    = (const float*)d_in[1];  // [1024]
    const float* A_raw = (const float*)d_in[2];  // [1024, 1024]
    const float* B     = (const float*)d_in[3];  // [1024, 512]
    const float* c     = (const float*)d_in[4];  // [1024]
    float* out = (float*)d_out;                  // [16384, 1024]
    unsigned long long* slots = (unsigned long long*)d_ws;  // 4 x 1024 x 8B

    dim3 gemm_grid(T_STEPS / 64, HD / 64);       // 256 x 16
    gemm_bx_kernel<<<gemm_grid, 256, 0, stream>>>(x, B, c, out);
    init_slots_kernel<<<1, HD, 0, stream>>>(slots, h0);
    rnn_scan_kernel<<<64, 512, 0, stream>>>(A_raw, out, slots);
}